// Round 4
// baseline (102.543 us; speedup 1.0000x reference)
//
#include <hip/hip_runtime.h>

// LowBitMixIn: out[b,o,t] = sum_{d=1..7} mixer[o,(o-d)&1023] * x[b, perm[(o-d)&1023], t]
// B=16, F=1024, T=4096, float32. Memory-bound streaming.
//
// R4: kill the LDS pipe entirely (was ~70% busy on 7 ds_read_b32/iter for
// wave-uniform coefs). Coefs+perm live in VGPRs (one coalesced prologue load
// each) and are extracted per-row via v_readlane with compile-time lane
// indices -> SGPRs. Hot loop VMEM = 1 row load + 1 nontemporal store.

#define F_DIM 1024
#define T_DIM 4096
#define T4 (T_DIM / 4)   // 1024 float4 per row
#define OCH 32           // o-rows per wave
#define ROWS_PER_BLOCK 128

typedef float fvec4 __attribute__((ext_vector_type(4)));

// coefPacked[o*8 + (d-1)] = mixer[o, (o-d)&1023], d=1..7; slot 7 = 0
__global__ __launch_bounds__(256) void prep_kernel(const float* __restrict__ mixer,
                                                   float* __restrict__ coefPacked) {
    const int o = blockIdx.x * 256 + threadIdx.x;   // 0..1023
#pragma unroll
    for (int j = 0; j < 8; ++j) {
        float c = 0.f;
        if (j < 7) c = mixer[(size_t)o * F_DIM + ((o - (j + 1)) & (F_DIM - 1))];
        coefPacked[o * 8 + j] = c;
    }
}

__global__ __launch_bounds__(256, 6) void lowbit_mix_kernel(
    const float* __restrict__ x, const float* __restrict__ coefPacked,
    const int* __restrict__ perm, float* __restrict__ out)
{
    const int tid  = threadIdx.x;
    const int lane = tid & 63;
    const int w    = tid >> 6;                               // wave 0..3
    const int t4   = blockIdx.x * 64 + lane;                 // float4 index along t
    const int o0   = blockIdx.y * ROWS_PER_BLOCK + w * OCH;  // wave's first output row
    const int b    = blockIdx.z;

    // wave-register aux data:
    // vperm: lane L holds perm[(o0-8+L)&1023]  (row o0+oi's new input -> lane 8+oi)
    const int vperm = perm[(o0 - 8 + lane) & (F_DIM - 1)];
    // vc: lane L holds coefPacked[o0*8 + 4L .. 4L+3]  (coef(oi,d) -> lane oi*2+((d-1)>>2), comp (d-1)&3)
    const fvec4 vc = *reinterpret_cast<const fvec4*>(&coefPacked[(size_t)o0 * 8 + lane * 4]);

    const fvec4* __restrict__ xb =
        reinterpret_cast<const fvec4*>(x) + (size_t)b * F_DIM * T4;
    fvec4* __restrict__ ob =
        reinterpret_cast<fvec4*>(out) + (size_t)b * F_DIM * T4;

    // Rolling window: win[k] = x-row for input index i = o-7+k (k=0..6)
    fvec4 win[7];
#pragma unroll
    for (int k = 0; k < 7; ++k) {
        const int pi = __builtin_amdgcn_readlane(vperm, 1 + k);   // perm[(o0-7+k)&1023]
        win[k] = xb[(size_t)pi * T4 + t4];
    }

#pragma unroll
    for (int oi = 0; oi < OCH; ++oi) {
        const int o = o0 + oi;

        // prefetch next window row (input index i = o), consumed end of next iter
        fvec4 nxt;
        if (oi != OCH - 1) {
            const int pi = __builtin_amdgcn_readlane(vperm, 8 + oi);
            nxt = xb[(size_t)pi * T4 + t4];
        }

        fvec4 acc = (fvec4)(0.f);
        // oldest (d=7) first ... newest (d=1) last -> max slack on the freshest load
#pragma unroll
        for (int d = 7; d >= 1; --d) {
            const int e    = (d - 1);
            const int ln   = oi * 2 + (e >> 2);                  // compile-time constant
            const float c  = __uint_as_float(
                (unsigned)__builtin_amdgcn_readlane(__float_as_uint(vc[e & 3]), ln));
            acc += c * win[7 - d];
        }
        __builtin_nontemporal_store(acc, &ob[(size_t)o * T4 + t4]);

        if (oi != OCH - 1) {
#pragma unroll
            for (int k = 0; k < 6; ++k) win[k] = win[k + 1];
            win[6] = nxt;
        }
    }
}

extern "C" void kernel_launch(void* const* d_in, const int* in_sizes, int n_in,
                              void* d_out, int out_size, void* d_ws, size_t ws_size,
                              hipStream_t stream) {
    const float* x     = (const float*)d_in[0];   // (16, 1024, 4096) f32
    const float* mixer = (const float*)d_in[1];   // (1024, 1024) f32
    const int*   perm  = (const int*)d_in[2];     // (1024,) i32
    float*       out   = (float*)d_out;           // (16, 1024, 4096) f32
    float*       coefPacked = (float*)d_ws;       // 1024*8 floats = 32 KB

    prep_kernel<<<dim3(4), dim3(256), 0, stream>>>(mixer, coefPacked);

    dim3 grid(T_DIM / 256,                 // 16 t-chunks (256 floats each)
              F_DIM / ROWS_PER_BLOCK,      // 8 o-tiles (128 rows: 4 waves x 32)
              16);                         // batch
    dim3 block(256);
    lowbit_mix_kernel<<<grid, block, 0, stream>>>(x, coefPacked, perm, out);
}